// Round 1
// baseline (3414.001 us; speedup 1.0000x reference)
//
#include <hip/hip_runtime.h>
#include <math.h>

// Dims (fixed by the problem)
#define B_  256
#define T_  64
#define D_  6400
#define H_  1000
#define A_  4

#define BM 128
#define BN 128
#define BK 16

// ---------------------------------------------------------------------------
// Kernel 1: C1[t][b][h] = x[b][t][:] . W1[h][:] + b1[h]
// A = x viewed as [M=B*T, K=D] row-major (m = b*64 + t)
// B = W1 [H, D] row-major (NT gemm: both operands K-contiguous)
// C1 stored [T][B][H] so the recurrent kernel reads it coalesced per step.
// ---------------------------------------------------------------------------
__global__ __launch_bounds__(256) void gemm1_kernel(
    const float* __restrict__ x, const float* __restrict__ W1,
    const float* __restrict__ b1, float* __restrict__ C1) {
  __shared__ float As[BK][BM + 4];
  __shared__ float Bs[BK][BN + 4];

  const int tid = threadIdx.x;
  const int m0 = blockIdx.y * BM;
  const int n0 = blockIdx.x * BN;
  const int tx = tid & 15;   // 0..15 -> 8 columns each
  const int ty = tid >> 4;   // 0..15 -> 8 rows each

  const int row = tid >> 2;  // 0..63 (staging row within half-tile)
  const int col4 = tid & 3;  // float4 column 0..3 (BK=16 -> 4 float4)

  float acc[8][8];
#pragma unroll
  for (int i = 0; i < 8; ++i)
#pragma unroll
    for (int j = 0; j < 8; ++j) acc[i][j] = 0.0f;

  for (int k0 = 0; k0 < D_; k0 += BK) {
    // ---- stage global -> regs (2 rows of A, 2 rows of B per thread) ----
    float4 av[2], bv[2];
#pragma unroll
    for (int i = 0; i < 2; ++i) {
      const int r = row + 64 * i;
      av[i] = *(const float4*)(x + (size_t)(m0 + r) * D_ + k0 + col4 * 4);
      const int h = n0 + r;
      if (h < H_) {
        bv[i] = *(const float4*)(W1 + (size_t)h * D_ + k0 + col4 * 4);
      } else {
        bv[i] = make_float4(0.f, 0.f, 0.f, 0.f);
      }
    }
    __syncthreads();
    // ---- regs -> LDS (transposed: [k][m]) ----
#pragma unroll
    for (int i = 0; i < 2; ++i) {
      const int r = row + 64 * i;
      As[col4 * 4 + 0][r] = av[i].x;
      As[col4 * 4 + 1][r] = av[i].y;
      As[col4 * 4 + 2][r] = av[i].z;
      As[col4 * 4 + 3][r] = av[i].w;
      Bs[col4 * 4 + 0][r] = bv[i].x;
      Bs[col4 * 4 + 1][r] = bv[i].y;
      Bs[col4 * 4 + 2][r] = bv[i].z;
      Bs[col4 * 4 + 3][r] = bv[i].w;
    }
    __syncthreads();
    // ---- compute ----
#pragma unroll
    for (int k = 0; k < BK; ++k) {
      const float4 a0 = *(const float4*)&As[k][ty * 8];
      const float4 a1 = *(const float4*)&As[k][ty * 8 + 4];
      const float4 b0 = *(const float4*)&Bs[k][tx * 8];
      const float4 b1v = *(const float4*)&Bs[k][tx * 8 + 4];
      const float ar[8] = {a0.x, a0.y, a0.z, a0.w, a1.x, a1.y, a1.z, a1.w};
      const float br[8] = {b0.x, b0.y, b0.z, b0.w, b1v.x, b1v.y, b1v.z, b1v.w};
#pragma unroll
      for (int i = 0; i < 8; ++i)
#pragma unroll
        for (int j = 0; j < 8; ++j) acc[i][j] = fmaf(ar[i], br[j], acc[i][j]);
    }
    __syncthreads();
  }

  // ---- epilogue: +b1, scatter rows to [T][B][H] ----
  const int h0 = n0 + tx * 8;  // multiple of 8; H_=1000 is multiple of 8
  if (h0 < H_) {
    float bias[8];
#pragma unroll
    for (int j = 0; j < 8; ++j) bias[j] = b1[h0 + j];
#pragma unroll
    for (int i = 0; i < 8; ++i) {
      const int m = m0 + ty * 8 + i;
      const int bb = m >> 6;   // batch
      const int tt = m & 63;   // timestep
      float* op = C1 + (size_t)tt * (B_ * H_) + (size_t)bb * H_ + h0;
      float4 r0, r1;
      r0.x = acc[i][0] + bias[0];
      r0.y = acc[i][1] + bias[1];
      r0.z = acc[i][2] + bias[2];
      r0.w = acc[i][3] + bias[3];
      r1.x = acc[i][4] + bias[4];
      r1.y = acc[i][5] + bias[5];
      r1.z = acc[i][6] + bias[6];
      r1.w = acc[i][7] + bias[7];
      *(float4*)(op) = r0;
      *(float4*)(op + 4) = r1;
    }
  }
}

// ---------------------------------------------------------------------------
// Kernel 2: recurrent LIF dynamics. One block per batch element.
// Thread tid owns hidden neurons h = tid, tid+256, tid+512, tid+768 (<1000).
// Layer-2 (A=4) reduction done with wave shuffles + tiny LDS.
// ---------------------------------------------------------------------------
__device__ __forceinline__ float sigmoid_f(float z) {
  return 1.0f / (1.0f + expf(-z));
}

__global__ __launch_bounds__(256) void snn_seq_kernel(
    const float* __restrict__ C1, const float* __restrict__ u1,
    const float* __restrict__ W2, const float* __restrict__ b2,
    const float* __restrict__ u2, float* __restrict__ out) {
  const int b = blockIdx.x;
  const int tid = threadIdx.x;
  const int lane = tid & 63;
  const int wv = tid >> 6;

  __shared__ float sW2[A_ * H_];  // 16 KB
  __shared__ float sRed[4][A_];

  for (int i = tid; i < A_ * H_; i += 256) sW2[i] = W2[i];
  __syncthreads();

  float mem1[4] = {0.f, 0.f, 0.f, 0.f};
  float th1[4] = {0.f, 0.f, 0.f, 0.f};
  float mem2[A_] = {0.f, 0.f, 0.f, 0.f};
  float th2[A_] = {0.f, 0.f, 0.f, 0.f};
  float scnt[A_] = {0.f, 0.f, 0.f, 0.f};

  for (int t = 0; t < T_; ++t) {
    const float* c1p = C1 + (size_t)t * (B_ * H_) + (size_t)b * H_;
    const float* u1p = u1 + (size_t)t * (B_ * H_) + (size_t)b * H_;
    float part[A_] = {0.f, 0.f, 0.f, 0.f};
#pragma unroll
    for (int k = 0; k < 4; ++k) {
      const int h = k * 256 + tid;
      if (h < H_) {
        const float cur = c1p[h];
        float m = fmaf(0.9f, mem1[k], cur);
        const float z = m - (1.0f + th1[k]);
        const float p = sigmoid_f(z);
        const float spk = (u1p[h] < p) ? 1.0f : 0.0f;
        m = (spk != 0.0f) ? 0.0f : m;
        th1[k] = fmaf(0.9f, th1[k], 0.05f * spk);
        mem1[k] = m;
        if (spk != 0.0f) {
          part[0] += sW2[h];
          part[1] += sW2[H_ + h];
          part[2] += sW2[2 * H_ + h];
          part[3] += sW2[3 * H_ + h];
        }
      }
    }
    // wave-level tree reduce (64 lanes)
#pragma unroll
    for (int off = 32; off >= 1; off >>= 1) {
#pragma unroll
      for (int a = 0; a < A_; ++a) part[a] += __shfl_down(part[a], off);
    }
    if (lane == 0) {
      sRed[wv][0] = part[0];
      sRed[wv][1] = part[1];
      sRed[wv][2] = part[2];
      sRed[wv][3] = part[3];
    }
    __syncthreads();
    if (tid == 0) {
#pragma unroll
      for (int a = 0; a < A_; ++a) {
        const float cur2 =
            sRed[0][a] + sRed[1][a] + sRed[2][a] + sRed[3][a] + b2[a];
        float m = fmaf(0.9f, mem2[a], cur2);
        const float z = m - (1.0f + th2[a]);
        const float p = sigmoid_f(z);
        const float u = u2[(size_t)t * (B_ * A_) + b * A_ + a];
        const float spk = (u < p) ? 1.0f : 0.0f;
        mem2[a] = (spk != 0.0f) ? 0.0f : m;
        th2[a] = fmaf(0.9f, th2[a], 0.05f * spk);
        scnt[a] += spk;
      }
    }
    __syncthreads();
  }

  if (tid == 0) {
#pragma unroll
    for (int a = 0; a < A_; ++a) out[b * A_ + a] = scnt[a] * (1.0f / 64.0f);
  }
}

extern "C" void kernel_launch(void* const* d_in, const int* in_sizes, int n_in,
                              void* d_out, int out_size, void* d_ws,
                              size_t ws_size, hipStream_t stream) {
  const float* x = (const float*)d_in[0];   // [B,T,D]
  const float* W1 = (const float*)d_in[1];  // [H,D]
  const float* b1 = (const float*)d_in[2];  // [H]
  const float* W2 = (const float*)d_in[3];  // [A,H]
  const float* b2 = (const float*)d_in[4];  // [A]
  const float* u1 = (const float*)d_in[5];  // [T,B,H]
  const float* u2 = (const float*)d_in[6];  // [T,B,A]
  float* out = (float*)d_out;               // [B,A]
  float* C1 = (float*)d_ws;                 // [T,B,H] = 65.536 MB scratch

  dim3 g1((H_ + BN - 1) / BN, (B_ * T_) / BM);  // (8, 128)
  gemm1_kernel<<<g1, 256, 0, stream>>>(x, W1, b1, C1);
  snn_seq_kernel<<<B_, 256, 0, stream>>>(C1, u1, W2, b2, u2, out);
}

// Round 2
// 3216.103 us; speedup vs baseline: 1.0615x; 1.0615x over previous
//
#include <hip/hip_runtime.h>
#include <math.h>

// Dims (fixed by the problem)
#define B_  256
#define T_  64
#define D_  6400
#define H_  1000
#define A_  4

#define BM 128
#define BN 128
#define BK 16

// ---------------------------------------------------------------------------
// Kernel 1: C1[t][b][h] = x[b][t][:] . W1[h][:] + b1[h]
// A = x viewed as [M=B*T, K=D] row-major (m = b*64 + t)
// B = W1 [H, D] row-major (NT gemm: both operands K-contiguous)
// C1 stored [T][B][H] so the recurrent kernel reads it coalesced per step.
//
// LDS layout [k][m], row stride BM+4=132 floats:
//   - staging stores (4 consecutive rows, same col per lane): banks
//     (col4*16 + r) % 32 -> exact 2-way -> free (m136).
//   - compute reads split as float4 at {q*4, 64+q*4}: banks (q*4)%32 ->
//     2-way -> free. (The old q*8 split was 4-way = 1.58x tax.)
// ---------------------------------------------------------------------------
__global__ __launch_bounds__(256) void gemm1_kernel(
    const float* __restrict__ x, const float* __restrict__ W1,
    const float* __restrict__ b1, float* __restrict__ C1) {
  __shared__ float As[BK][BM + 4];
  __shared__ float Bs[BK][BN + 4];

  const int tid = threadIdx.x;
  const int m0 = blockIdx.y * BM;
  const int n0 = blockIdx.x * BN;
  const int tx = tid & 15;   // 0..15 -> cols {tx*4..+3, 64+tx*4..+3}
  const int ty = tid >> 4;   // 0..15 -> rows {ty*4..+3, 64+ty*4..+3}

  const int row = tid >> 2;  // 0..63 (staging row within half-tile)
  const int col4 = tid & 3;  // float4 column 0..3 (BK=16 -> 4 float4)

  float acc[8][8];
#pragma unroll
  for (int i = 0; i < 8; ++i)
#pragma unroll
    for (int j = 0; j < 8; ++j) acc[i][j] = 0.0f;

  // ---- prefetch first tile into registers ----
  float4 av[2], bv[2];
#pragma unroll
  for (int i = 0; i < 2; ++i) {
    const int r = row + 64 * i;
    av[i] = *(const float4*)(x + (size_t)(m0 + r) * D_ + col4 * 4);
    const int h = n0 + r;
    bv[i] = (h < H_) ? *(const float4*)(W1 + (size_t)h * D_ + col4 * 4)
                     : make_float4(0.f, 0.f, 0.f, 0.f);
  }

  for (int k0 = 0; k0 < D_; k0 += BK) {
    __syncthreads();
    // ---- regs -> LDS (transposed: [k][m]) ----
#pragma unroll
    for (int i = 0; i < 2; ++i) {
      const int r = row + 64 * i;
      As[col4 * 4 + 0][r] = av[i].x;
      As[col4 * 4 + 1][r] = av[i].y;
      As[col4 * 4 + 2][r] = av[i].z;
      As[col4 * 4 + 3][r] = av[i].w;
      Bs[col4 * 4 + 0][r] = bv[i].x;
      Bs[col4 * 4 + 1][r] = bv[i].y;
      Bs[col4 * 4 + 2][r] = bv[i].z;
      Bs[col4 * 4 + 3][r] = bv[i].w;
    }
    __syncthreads();
    // ---- issue next tile's global loads (latency hides under compute) ----
    if (k0 + BK < D_) {
      const int kn = k0 + BK;
#pragma unroll
      for (int i = 0; i < 2; ++i) {
        const int r = row + 64 * i;
        av[i] = *(const float4*)(x + (size_t)(m0 + r) * D_ + kn + col4 * 4);
        const int h = n0 + r;
        bv[i] = (h < H_) ? *(const float4*)(W1 + (size_t)h * D_ + kn + col4 * 4)
                         : make_float4(0.f, 0.f, 0.f, 0.f);
      }
    }
    // ---- compute ----
#pragma unroll
    for (int k = 0; k < BK; ++k) {
      const float4 a0 = *(const float4*)&As[k][ty * 4];
      const float4 a1 = *(const float4*)&As[k][64 + ty * 4];
      const float4 b0 = *(const float4*)&Bs[k][tx * 4];
      const float4 b1v = *(const float4*)&Bs[k][64 + tx * 4];
      const float ar[8] = {a0.x, a0.y, a0.z, a0.w, a1.x, a1.y, a1.z, a1.w};
      const float br[8] = {b0.x, b0.y, b0.z, b0.w, b1v.x, b1v.y, b1v.z, b1v.w};
#pragma unroll
      for (int i = 0; i < 8; ++i)
#pragma unroll
        for (int j = 0; j < 8; ++j) acc[i][j] = fmaf(ar[i], br[j], acc[i][j]);
    }
  }

  // ---- epilogue: +b1, scatter rows to [T][B][H] ----
  // rows: i<4 -> m0+ty*4+i ; i>=4 -> m0+64+ty*4+(i-4)
  // cols: j<4 -> n0+tx*4+j ; j>=4 -> n0+64+tx*4+(j-4)
  const int h0 = n0 + tx * 4;       // multiple of 4; H_=1000 % 4 == 0
  const int h1 = n0 + 64 + tx * 4;
  float4 bias0 = (h0 < H_) ? *(const float4*)(b1 + h0)
                           : make_float4(0.f, 0.f, 0.f, 0.f);
  float4 bias1 = (h1 < H_) ? *(const float4*)(b1 + h1)
                           : make_float4(0.f, 0.f, 0.f, 0.f);
#pragma unroll
  for (int ih = 0; ih < 2; ++ih) {
#pragma unroll
    for (int i2 = 0; i2 < 4; ++i2) {
      const int i = ih * 4 + i2;
      const int m = m0 + ih * 64 + ty * 4 + i2;
      const int bb = m >> 6;   // batch
      const int tt = m & 63;   // timestep
      float* op = C1 + (size_t)tt * (B_ * H_) + (size_t)bb * H_;
      if (h0 < H_) {
        float4 r0;
        r0.x = acc[i][0] + bias0.x;
        r0.y = acc[i][1] + bias0.y;
        r0.z = acc[i][2] + bias0.z;
        r0.w = acc[i][3] + bias0.w;
        *(float4*)(op + h0) = r0;
      }
      if (h1 < H_) {
        float4 r1;
        r1.x = acc[i][4] + bias1.x;
        r1.y = acc[i][5] + bias1.y;
        r1.z = acc[i][6] + bias1.z;
        r1.w = acc[i][7] + bias1.w;
        *(float4*)(op + h1) = r1;
      }
    }
  }
}

// ---------------------------------------------------------------------------
// Kernel 2: recurrent LIF dynamics. One block per batch element.
// Thread tid owns hidden neurons h = tid, tid+256, tid+512, tid+768 (<1000).
// Layer-2 (A=4) reduction done with wave shuffles + tiny LDS.
// ---------------------------------------------------------------------------
__device__ __forceinline__ float sigmoid_f(float z) {
  return 1.0f / (1.0f + expf(-z));
}

__global__ __launch_bounds__(256) void snn_seq_kernel(
    const float* __restrict__ C1, const float* __restrict__ u1,
    const float* __restrict__ W2, const float* __restrict__ b2,
    const float* __restrict__ u2, float* __restrict__ out) {
  const int b = blockIdx.x;
  const int tid = threadIdx.x;
  const int lane = tid & 63;
  const int wv = tid >> 6;

  __shared__ float sW2[A_ * H_];  // 16 KB
  __shared__ float sRed[4][A_];

  for (int i = tid; i < A_ * H_; i += 256) sW2[i] = W2[i];
  __syncthreads();

  float mem1[4] = {0.f, 0.f, 0.f, 0.f};
  float th1[4] = {0.f, 0.f, 0.f, 0.f};
  float mem2[A_] = {0.f, 0.f, 0.f, 0.f};
  float th2[A_] = {0.f, 0.f, 0.f, 0.f};
  float scnt[A_] = {0.f, 0.f, 0.f, 0.f};

  for (int t = 0; t < T_; ++t) {
    const float* c1p = C1 + (size_t)t * (B_ * H_) + (size_t)b * H_;
    const float* u1p = u1 + (size_t)t * (B_ * H_) + (size_t)b * H_;
    float part[A_] = {0.f, 0.f, 0.f, 0.f};
#pragma unroll
    for (int k = 0; k < 4; ++k) {
      const int h = k * 256 + tid;
      if (h < H_) {
        const float cur = c1p[h];
        float m = fmaf(0.9f, mem1[k], cur);
        const float z = m - (1.0f + th1[k]);
        const float p = sigmoid_f(z);
        const float spk = (u1p[h] < p) ? 1.0f : 0.0f;
        m = (spk != 0.0f) ? 0.0f : m;
        th1[k] = fmaf(0.9f, th1[k], 0.05f * spk);
        mem1[k] = m;
        if (spk != 0.0f) {
          part[0] += sW2[h];
          part[1] += sW2[H_ + h];
          part[2] += sW2[2 * H_ + h];
          part[3] += sW2[3 * H_ + h];
        }
      }
    }
    // wave-level tree reduce (64 lanes)
#pragma unroll
    for (int off = 32; off >= 1; off >>= 1) {
#pragma unroll
      for (int a = 0; a < A_; ++a) part[a] += __shfl_down(part[a], off);
    }
    if (lane == 0) {
      sRed[wv][0] = part[0];
      sRed[wv][1] = part[1];
      sRed[wv][2] = part[2];
      sRed[wv][3] = part[3];
    }
    __syncthreads();
    if (tid == 0) {
#pragma unroll
      for (int a = 0; a < A_; ++a) {
        const float cur2 =
            sRed[0][a] + sRed[1][a] + sRed[2][a] + sRed[3][a] + b2[a];
        float m = fmaf(0.9f, mem2[a], cur2);
        const float z = m - (1.0f + th2[a]);
        const float p = sigmoid_f(z);
        const float u = u2[(size_t)t * (B_ * A_) + b * A_ + a];
        const float spk = (u < p) ? 1.0f : 0.0f;
        mem2[a] = (spk != 0.0f) ? 0.0f : m;
        th2[a] = fmaf(0.9f, th2[a], 0.05f * spk);
        scnt[a] += spk;
      }
    }
    __syncthreads();
  }

  if (tid == 0) {
#pragma unroll
    for (int a = 0; a < A_; ++a) out[b * A_ + a] = scnt[a] * (1.0f / 64.0f);
  }
}

extern "C" void kernel_launch(void* const* d_in, const int* in_sizes, int n_in,
                              void* d_out, int out_size, void* d_ws,
                              size_t ws_size, hipStream_t stream) {
  const float* x = (const float*)d_in[0];   // [B,T,D]
  const float* W1 = (const float*)d_in[1];  // [H,D]
  const float* b1 = (const float*)d_in[2];  // [H]
  const float* W2 = (const float*)d_in[3];  // [A,H]
  const float* b2 = (const float*)d_in[4];  // [A]
  const float* u1 = (const float*)d_in[5];  // [T,B,H]
  const float* u2 = (const float*)d_in[6];  // [T,B,A]
  float* out = (float*)d_out;               // [B,A]
  float* C1 = (float*)d_ws;                 // [T,B,H] = 65.536 MB scratch

  dim3 g1((H_ + BN - 1) / BN, (B_ * T_) / BM);  // (8, 128)
  gemm1_kernel<<<g1, 256, 0, stream>>>(x, W1, b1, C1);
  snn_seq_kernel<<<B_, 256, 0, stream>>>(C1, u1, W2, b2, u2, out);
}

// Round 3
// 3004.315 us; speedup vs baseline: 1.1364x; 1.0705x over previous
//
#include <hip/hip_runtime.h>
#include <math.h>

// Dims (fixed by the problem)
#define B_  256
#define T_  64
#define D_  6400
#define H_  1000
#define A_  4

#define BM 256
#define BN 128
#define BK 16

typedef float v2f __attribute__((ext_vector_type(2)));

// v_pk_fma_f32: D.lo = sel(S0)*S1.lo + S2.lo ; D.hi = sel_hi(S0)*S1.hi + S2.hi
// LO: use S0.lo for both halves (op_sel[0]=0, op_sel_hi[0]=0)
// HI: use S0.hi for both halves (op_sel[0]=1, op_sel_hi[0]=1)
#define PK_FMA_LO(acc, a, b)                                          \
  asm("v_pk_fma_f32 %0, %1, %2, %0 op_sel:[0,0,0] op_sel_hi:[0,1,1]" \
      : "+v"(acc)                                                     \
      : "v"(a), "v"(b))
#define PK_FMA_HI(acc, a, b)                                          \
  asm("v_pk_fma_f32 %0, %1, %2, %0 op_sel:[1,0,0] op_sel_hi:[1,1,1]" \
      : "+v"(acc)                                                     \
      : "v"(a), "v"(b))

// ---------------------------------------------------------------------------
// Kernel 1: C1[t][b][h] = x[b][t][:] . W1[h][:] + b1[h]
// Block tile 256(M) x 128(N), BK=16; thread micro-tile 16x8 via v_pk_fma_f32
// (2 fp32 FMA per instruction — the only path to the 157 TF fp32 rate).
// Per-element FMA order (k ascending, IEEE fma) is identical to the scalar
// version -> bitwise-identical C1 -> identical spikes.
// ---------------------------------------------------------------------------
__global__ __launch_bounds__(256, 2) void gemm1_kernel(
    const float* __restrict__ x, const float* __restrict__ W1,
    const float* __restrict__ b1, float* __restrict__ C1) {
  __shared__ float As[BK][BM + 4];  // [k][m], stride 260
  __shared__ float Bs[BK][BN + 4];  // [k][n], stride 132

  const int tid = threadIdx.x;
  const int m0 = blockIdx.y * BM;
  const int n0 = blockIdx.x * BN;
  const int tx = tid & 15;   // cols {tx*4..+3, 64+tx*4..+3}
  const int ty = tid >> 4;   // rows {ty*4..+3, +64, +128, +192}

  const int row = tid >> 2;  // 0..63 staging row within 64-row chunk
  const int col4 = tid & 3;  // float4 column 0..3 (BK=16)

  v2f acc2[16][4];
#pragma unroll
  for (int i = 0; i < 16; ++i)
#pragma unroll
    for (int j = 0; j < 4; ++j) acc2[i][j] = (v2f){0.f, 0.f};

  // ---- prefetch first tile into registers ----
  float4 av[4], bv[2];
#pragma unroll
  for (int i = 0; i < 4; ++i)
    av[i] = *(const float4*)(x + (size_t)(m0 + row + 64 * i) * D_ + col4 * 4);
#pragma unroll
  for (int i = 0; i < 2; ++i) {
    const int h = n0 + row + 64 * i;
    bv[i] = (h < H_) ? *(const float4*)(W1 + (size_t)h * D_ + col4 * 4)
                     : make_float4(0.f, 0.f, 0.f, 0.f);
  }

  for (int k0 = 0; k0 < D_; k0 += BK) {
    __syncthreads();
    // ---- regs -> LDS (transposed). Store banks: 2-way -> free. ----
#pragma unroll
    for (int i = 0; i < 4; ++i) {
      const int r = row + 64 * i;
      As[col4 * 4 + 0][r] = av[i].x;
      As[col4 * 4 + 1][r] = av[i].y;
      As[col4 * 4 + 2][r] = av[i].z;
      As[col4 * 4 + 3][r] = av[i].w;
    }
#pragma unroll
    for (int i = 0; i < 2; ++i) {
      const int r = row + 64 * i;
      Bs[col4 * 4 + 0][r] = bv[i].x;
      Bs[col4 * 4 + 1][r] = bv[i].y;
      Bs[col4 * 4 + 2][r] = bv[i].z;
      Bs[col4 * 4 + 3][r] = bv[i].w;
    }
    __syncthreads();
    // ---- issue next tile's global loads (hide under compute) ----
    if (k0 + BK < D_) {
      const int kn = k0 + BK;
#pragma unroll
      for (int i = 0; i < 4; ++i)
        av[i] =
            *(const float4*)(x + (size_t)(m0 + row + 64 * i) * D_ + kn + col4 * 4);
#pragma unroll
      for (int i = 0; i < 2; ++i) {
        const int h = n0 + row + 64 * i;
        bv[i] = (h < H_)
                    ? *(const float4*)(W1 + (size_t)h * D_ + kn + col4 * 4)
                    : make_float4(0.f, 0.f, 0.f, 0.f);
      }
    }
    // ---- compute: 16 k-steps x 64 pk-FMA ----
#pragma unroll
    for (int k = 0; k < BK; ++k) {
      const float4 a0 = *(const float4*)&As[k][ty * 4];
      const float4 a1 = *(const float4*)&As[k][64 + ty * 4];
      const float4 a2 = *(const float4*)&As[k][128 + ty * 4];
      const float4 a3 = *(const float4*)&As[k][192 + ty * 4];
      const float4 b0 = *(const float4*)&Bs[k][tx * 4];
      const float4 b1v = *(const float4*)&Bs[k][64 + tx * 4];
      v2f ap[8] = {{a0.x, a0.y}, {a0.z, a0.w}, {a1.x, a1.y}, {a1.z, a1.w},
                   {a2.x, a2.y}, {a2.z, a2.w}, {a3.x, a3.y}, {a3.z, a3.w}};
      v2f bp[4] = {{b0.x, b0.y}, {b0.z, b0.w}, {b1v.x, b1v.y}, {b1v.z, b1v.w}};
#pragma unroll
      for (int p = 0; p < 8; ++p) {
#pragma unroll
        for (int j = 0; j < 4; ++j) {
          PK_FMA_LO(acc2[2 * p][j], ap[p], bp[j]);
          PK_FMA_HI(acc2[2 * p + 1][j], ap[p], bp[j]);
        }
      }
    }
  }

  // ---- epilogue: +b1, scatter rows to [T][B][H] ----
  // A-float f (0..15) -> row m0 + 64*(f>>2) + ty*4 + (f&3)
  // cols: acc2[f][0..1] -> h0+0..3 ; acc2[f][2..3] -> h1+0..3
  const int h0 = n0 + tx * 4;
  const int h1 = n0 + 64 + tx * 4;
  float4 bias0 = (h0 < H_) ? *(const float4*)(b1 + h0)
                           : make_float4(0.f, 0.f, 0.f, 0.f);
  float4 bias1 = (h1 < H_) ? *(const float4*)(b1 + h1)
                           : make_float4(0.f, 0.f, 0.f, 0.f);
#pragma unroll
  for (int f = 0; f < 16; ++f) {
    const int m = m0 + 64 * (f >> 2) + ty * 4 + (f & 3);
    const int bb = m >> 6;  // batch
    const int tt = m & 63;  // timestep
    float* op = C1 + (size_t)tt * (B_ * H_) + (size_t)bb * H_;
    if (h0 < H_) {
      float4 r;
      r.x = acc2[f][0].x + bias0.x;
      r.y = acc2[f][0].y + bias0.y;
      r.z = acc2[f][1].x + bias0.z;
      r.w = acc2[f][1].y + bias0.w;
      *(float4*)(op + h0) = r;
    }
    if (h1 < H_) {
      float4 r;
      r.x = acc2[f][2].x + bias1.x;
      r.y = acc2[f][2].y + bias1.y;
      r.z = acc2[f][3].x + bias1.z;
      r.w = acc2[f][3].y + bias1.w;
      *(float4*)(op + h1) = r;
    }
  }
}

// ---------------------------------------------------------------------------
// Kernel 2: recurrent LIF dynamics. One block per batch element.
// ---------------------------------------------------------------------------
__device__ __forceinline__ float sigmoid_f(float z) {
  return 1.0f / (1.0f + expf(-z));
}

__global__ __launch_bounds__(256) void snn_seq_kernel(
    const float* __restrict__ C1, const float* __restrict__ u1,
    const float* __restrict__ W2, const float* __restrict__ b2,
    const float* __restrict__ u2, float* __restrict__ out) {
  const int b = blockIdx.x;
  const int tid = threadIdx.x;
  const int lane = tid & 63;
  const int wv = tid >> 6;

  __shared__ float sW2[A_ * H_];  // 16 KB
  __shared__ float sRed[4][A_];

  for (int i = tid; i < A_ * H_; i += 256) sW2[i] = W2[i];
  __syncthreads();

  float mem1[4] = {0.f, 0.f, 0.f, 0.f};
  float th1[4] = {0.f, 0.f, 0.f, 0.f};
  float mem2[A_] = {0.f, 0.f, 0.f, 0.f};
  float th2[A_] = {0.f, 0.f, 0.f, 0.f};
  float scnt[A_] = {0.f, 0.f, 0.f, 0.f};

  for (int t = 0; t < T_; ++t) {
    const float* c1p = C1 + (size_t)t * (B_ * H_) + (size_t)b * H_;
    const float* u1p = u1 + (size_t)t * (B_ * H_) + (size_t)b * H_;
    float part[A_] = {0.f, 0.f, 0.f, 0.f};
#pragma unroll
    for (int k = 0; k < 4; ++k) {
      const int h = k * 256 + tid;
      if (h < H_) {
        const float cur = c1p[h];
        float m = fmaf(0.9f, mem1[k], cur);
        const float z = m - (1.0f + th1[k]);
        const float p = sigmoid_f(z);
        const float spk = (u1p[h] < p) ? 1.0f : 0.0f;
        m = (spk != 0.0f) ? 0.0f : m;
        th1[k] = fmaf(0.9f, th1[k], 0.05f * spk);
        mem1[k] = m;
        if (spk != 0.0f) {
          part[0] += sW2[h];
          part[1] += sW2[H_ + h];
          part[2] += sW2[2 * H_ + h];
          part[3] += sW2[3 * H_ + h];
        }
      }
    }
    // wave-level tree reduce (64 lanes)
#pragma unroll
    for (int off = 32; off >= 1; off >>= 1) {
#pragma unroll
      for (int a = 0; a < A_; ++a) part[a] += __shfl_down(part[a], off);
    }
    if (lane == 0) {
      sRed[wv][0] = part[0];
      sRed[wv][1] = part[1];
      sRed[wv][2] = part[2];
      sRed[wv][3] = part[3];
    }
    __syncthreads();
    if (tid == 0) {
#pragma unroll
      for (int a = 0; a < A_; ++a) {
        const float cur2 =
            sRed[0][a] + sRed[1][a] + sRed[2][a] + sRed[3][a] + b2[a];
        float m = fmaf(0.9f, mem2[a], cur2);
        const float z = m - (1.0f + th2[a]);
        const float p = sigmoid_f(z);
        const float u = u2[(size_t)t * (B_ * A_) + b * A_ + a];
        const float spk = (u < p) ? 1.0f : 0.0f;
        mem2[a] = (spk != 0.0f) ? 0.0f : m;
        th2[a] = fmaf(0.9f, th2[a], 0.05f * spk);
        scnt[a] += spk;
      }
    }
    __syncthreads();
  }

  if (tid == 0) {
#pragma unroll
    for (int a = 0; a < A_; ++a) out[b * A_ + a] = scnt[a] * (1.0f / 64.0f);
  }
}

extern "C" void kernel_launch(void* const* d_in, const int* in_sizes, int n_in,
                              void* d_out, int out_size, void* d_ws,
                              size_t ws_size, hipStream_t stream) {
  const float* x = (const float*)d_in[0];   // [B,T,D]
  const float* W1 = (const float*)d_in[1];  // [H,D]
  const float* b1 = (const float*)d_in[2];  // [H]
  const float* W2 = (const float*)d_in[3];  // [A,H]
  const float* b2 = (const float*)d_in[4];  // [A]
  const float* u1 = (const float*)d_in[5];  // [T,B,H]
  const float* u2 = (const float*)d_in[6];  // [T,B,A]
  float* out = (float*)d_out;               // [B,A]
  float* C1 = (float*)d_ws;                 // [T,B,H] = 65.536 MB scratch

  dim3 g1((H_ + BN - 1) / BN, (B_ * T_) / BM);  // (8, 64)
  gemm1_kernel<<<g1, 256, 0, stream>>>(x, W1, b1, C1);
  snn_seq_kernel<<<B_, 256, 0, stream>>>(C1, u1, W2, b2, u2, out);
}